// Round 16
// baseline (62.195 us; speedup 1.0000x reference)
//
#include <hip/hip_runtime.h>
#include <hip/hip_bf16.h>
#include <stdint.h>

// RNDiscriminator: B=64, d^2=64 positions, 26 features, g: 52->256->256, f: 256->1
// h1[i,j] = relu(u'[j] + v[i]); dominant cost sum_ij relu(h1 @ W2 + b2) = 34.4 GF bf16.
//
// R16: consumers use 32x32x16 MFMA (2x FLOP/instruction, higher ceiling) to
// attack the low-occupancy MFMA issue-rate limit that 5 schedule variants all
// hit (~37us). P/C structure from R15: 256 blocks x 768 thr, waves 0-3 produce
// h1 frags (frag-major, conflict-free), waves 4-11 consume (one 32-col tile
// each): Bf[16]=64 VGPR, acc[2][2] f32x16 (parity-split K chains). Flag-synced
// 4-deep ring, no barriers in the pair loop.

typedef float f32x4  __attribute__((ext_vector_type(4)));
typedef float f32x2  __attribute__((ext_vector_type(2)));
typedef float f32x16 __attribute__((ext_vector_type(16)));
typedef short short8 __attribute__((ext_vector_type(8)));
typedef int   int4v  __attribute__((ext_vector_type(4)));

#define NB 4   // ring depth

__device__ __forceinline__ uint32_t cvt_pk_bf16(float lo, float hi) {
    uint32_t r;
    asm("v_cvt_pk_bf16_f32 %0, %1, %2" : "=v"(r) : "v"(lo), "v"(hi));
    return r;
}
__device__ __forceinline__ f32x2 relu2(f32x2 a) {
    f32x2 z = (f32x2){0.f, 0.f};
    return __builtin_elementwise_max(a, z);
}
// h1 pair from packed-bf16 u + f32 v: relu(u+v) -> packed bf16
__device__ __forceinline__ uint32_t fuse2(uint32_t up, float vlo, float vhi) {
    f32x2 uu;
    uu.x = __uint_as_float(up << 16);
    uu.y = __uint_as_float(up & 0xFFFF0000u);
    f32x2 r = relu2(uu + (f32x2){vlo, vhi});
    return cvt_pk_bf16(r.x, r.y);
}
__device__ __forceinline__ void spin_eq(int* p, int val) {
    while (__hip_atomic_load(p, __ATOMIC_ACQUIRE, __HIP_MEMORY_SCOPE_WORKGROUP) != val)
        __builtin_amdgcn_s_sleep(1);
    __builtin_amdgcn_sched_barrier(0);
}
__device__ __forceinline__ void flag_release_add(int* p, int lane) {
    asm volatile("s_waitcnt lgkmcnt(0)" ::: "memory");
    if (lane == 0)
        __hip_atomic_fetch_add(p, 1, __ATOMIC_RELEASE, __HIP_MEMORY_SCOPE_WORKGROUP);
}

// K12: blocks 0..255: fused conv(8x8/s8)+relu+coords -> u,v rows.
//      blocks 256..287: pre-fragment W2 for 32x32x16 B-operand:
//      fid2 = ks*8 + nt; lane l holds w2[ks*16+(l>>5)*8+e][nt*32+(l&31)].
__global__ void k12_front(const float* __restrict__ img, const float* __restrict__ cw,
                          const float* __restrict__ cb, const float* __restrict__ w1,
                          const float* __restrict__ b1, const float* __restrict__ w2,
                          float* __restrict__ u, float* __restrict__ v,
                          short* __restrict__ w2f) {
    int g = blockIdx.x;
    int t = threadIdx.x;
    if (g >= 256) {
        int fi = (g - 256) * 4 + (t >> 6);   // 0..127
        int l = t & 63;
        int ks = fi >> 3, nt = fi & 7;
        int n  = nt * 32 + (l & 31);
        int k0 = ks * 16 + (l >> 5) * 8;
        float f[8];
        #pragma unroll
        for (int e = 0; e < 8; ++e) f[e] = w2[(k0 + e) * 256 + n];
        union { short8 s; uint32_t w[4]; } A;
        A.w[0] = cvt_pk_bf16(f[0], f[1]);
        A.w[1] = cvt_pk_bf16(f[2], f[3]);
        A.w[2] = cvt_pk_bf16(f[4], f[5]);
        A.w[3] = cvt_pk_bf16(f[6], f[7]);
        *(short8*)(w2f + (fi * 64 + l) * 8) = A.s;
        return;
    }
    __shared__ float xs[16][26];
    int b = g >> 2, q = g & 3, p0 = q * 16;

    for (int idx = t; idx < 416; idx += 256) {
        int pl = idx / 26;
        int ch = idx - pl * 26;
        int pos = p0 + pl;
        int r = pos >> 3, c = pos & 7;
        float val;
        if (ch < 24) {
            float s = cb[ch];
            #pragma unroll
            for (int ci = 0; ci < 3; ++ci)
                #pragma unroll
                for (int kr = 0; kr < 8; ++kr) {
                    const float* ip = img + ((b * 3 + ci) * 64 + r * 8 + kr) * 64 + c * 8;
                    const float* wp = cw + ((ch * 3 + ci) * 8 + kr) * 8;
                    #pragma unroll
                    for (int kc = 0; kc < 8; ++kc) s += ip[kc] * wp[kc];
                }
            val = fmaxf(s, 0.f);
        } else if (ch == 24) {
            val = -1.f + (2.f / 7.f) * (float)c;
        } else {
            val = -1.f + (2.f / 7.f) * (float)r;
        }
        xs[pl][ch] = val;
    }
    __syncthreads();

    int c = t;
    float bc = b1[c];
    float su[16], sv[16];
    #pragma unroll
    for (int r = 0; r < 16; ++r) { su[r] = bc; sv[r] = 0.f; }
    #pragma unroll 2
    for (int k = 0; k < 26; ++k) {
        float wu = w1[k * 256 + c];
        float wv2 = w1[(26 + k) * 256 + c];
        #pragma unroll
        for (int r = 0; r < 16; ++r) {
            float xv = xs[r][k];
            su[r] += xv * wu;
            sv[r] += xv * wv2;
        }
    }
    #pragma unroll
    for (int r = 0; r < 16; ++r) {
        int bj = b * 64 + p0 + r;
        u[bj * 256 + c] = su[r];
        v[bj * 256 + c] = sv[r];
    }
}

// ---- consumer macros: frag-major 32x32 A reads (contiguous, conflict-free) ----
// frag (wr, ks) at (wr*16 + ks)*1024 + lane*16
#define RD(A, KS)                                                      \
    { A[0] = *(const short8*)(cb0 + (KS) * 1024);                      \
      A[1] = *(const short8*)(cb0 + (16 + (KS)) * 1024); }

#define MM(A, KS, P)                                                   \
    acc[0][P] = __builtin_amdgcn_mfma_f32_32x32x16_bf16(A[0], Bf[KS], acc[0][P], 0, 0, 0); \
    acc[1][P] = __builtin_amdgcn_mfma_f32_32x32x16_bf16(A[1], Bf[KS], acc[1][P], 0, 0, 0);

__global__ __launch_bounds__(768, 3) void k3_pairs(
        const float* __restrict__ u, const float* __restrict__ v,
        const short* __restrict__ w2f, const float* __restrict__ b2,
        float* __restrict__ part) {
    __shared__ short h1s[NB][64 * 256];   // 128 KB ring; slot = 32 frags x 1 KB
    __shared__ float vs[16][256];         // 16 KB
    __shared__ int prod_cnt[16];
    __shared__ int cons_cnt[16];
    int t = threadIdx.x;
    int lane = t & 63, wv = t >> 6;       // wv 0..11
    int blk = blockIdx.x;                 // 0..255
    int b = blk & 63, i0 = (blk >> 6) * 16;

    if (t < 16) { prod_cnt[t] = 0; cons_cnt[t] = 0; }

    // stage the 16 v rows once (threads 0..511)
    if (t < 512) {
        int q = t >> 5, c8 = (t & 31) * 8;
        const float* vr = v + (b * 64 + i0 + q) * 256 + c8;
        *(float4*)&vs[q][c8]     = *(const float4*)vr;
        *(float4*)&vs[q][c8 + 4] = *(const float4*)(vr + 4);
    }

    if (wv < 4) {
        // ========== PRODUCER (waves 0-3, one per SIMD) ==========
        // thread owns frags fid = j*4 + wv (j=0..7): wr = fid>>4, ks = fid&15;
        // lane l: rows wr*32+(l&31), k = ks*16 + (l>>5)*8 ..+8 (packed bf16, 32 VGPR)
        uint32_t upk[8][4];
        #pragma unroll
        for (int j = 0; j < 8; ++j) {
            int fid = j * 4 + wv;
            int row = (fid >> 4) * 32 + (lane & 31);
            int k0 = (fid & 15) * 16 + (lane >> 5) * 8;
            const float* up = u + (b * 64 + row) * 256 + k0;
            f32x4 x0 = *(const f32x4*)up;
            f32x4 x1 = *(const f32x4*)(up + 4);
            upk[j][0] = cvt_pk_bf16(x0.x, x0.y);
            upk[j][1] = cvt_pk_bf16(x0.z, x0.w);
            upk[j][2] = cvt_pk_bf16(x1.x, x1.y);
            upk[j][3] = cvt_pk_bf16(x1.z, x1.w);
        }
        __syncthreads();   // vs ready; flags init'd

        #pragma unroll 1
        for (int q = 0; q < 16; ++q) {
            if (q >= NB) spin_eq(&cons_cnt[q - NB], 8);
            char* base = (char*)h1s[q & (NB - 1)] + lane * 16;
            #pragma unroll
            for (int j = 0; j < 8; ++j) {
                int fid = j * 4 + wv;
                int k0 = (fid & 15) * 16 + (lane >> 5) * 8;
                f32x4 v0 = *(const f32x4*)&vs[q][k0];
                f32x4 v1 = *(const f32x4*)&vs[q][k0 + 4];
                int4v d;
                d.x = (int)fuse2(upk[j][0], v0.x, v0.y);
                d.y = (int)fuse2(upk[j][1], v0.z, v0.w);
                d.z = (int)fuse2(upk[j][2], v1.x, v1.y);
                d.w = (int)fuse2(upk[j][3], v1.z, v1.w);
                *(int4v*)(base + fid * 1024) = d;
            }
            flag_release_add(&prod_cnt[q], lane);
        }
    } else {
        // ========== CONSUMER (waves 4-11, two per SIMD) ==========
        int wc = wv - 4;                  // 32-col tile: n = wc*32 + (lane&31)

        short8 Bf[16];
        #pragma unroll
        for (int ks = 0; ks < 16; ++ks)
            Bf[ks] = *(const short8*)(w2f + ((ks * 8 + wc) * 64 + lane) * 8);

        float bias = b2[wc * 32 + (lane & 31)];
        float csum = 0.f;
        __syncthreads();   // vs ready; flags init'd

        #pragma unroll 1
        for (int q = 0; q < 16; ++q) {
            spin_eq(&prod_cnt[q], 4);
            const char* cb0 = (const char*)h1s[q & (NB - 1)] + lane * 16;

            f32x16 acc[2][2];
            #pragma unroll
            for (int mi = 0; mi < 2; ++mi)
                #pragma unroll
                for (int p = 0; p < 2; ++p)
                    #pragma unroll
                    for (int r = 0; r < 16; ++r) acc[mi][p][r] = 0.f;

            short8 Aa[2], Ab[2];
            RD(Aa, 0) RD(Ab, 1)
            __builtin_amdgcn_s_setprio(1);
            MM(Aa, 0, 0)  RD(Aa, 2)
            MM(Ab, 1, 1)  RD(Ab, 3)
            MM(Aa, 2, 0)  RD(Aa, 4)
            MM(Ab, 3, 1)  RD(Ab, 5)
            MM(Aa, 4, 0)  RD(Aa, 6)
            MM(Ab, 5, 1)  RD(Ab, 7)
            MM(Aa, 6, 0)  RD(Aa, 8)
            MM(Ab, 7, 1)  RD(Ab, 9)
            MM(Aa, 8, 0)  RD(Aa, 10)
            MM(Ab, 9, 1)  RD(Ab, 11)
            MM(Aa, 10, 0) RD(Aa, 12)
            MM(Ab, 11, 1) RD(Ab, 13)
            MM(Aa, 12, 0) RD(Aa, 14)
            MM(Ab, 13, 1) RD(Ab, 15)
            MM(Aa, 14, 0)
            MM(Ab, 15, 1)
            __builtin_amdgcn_s_setprio(0);

            // epilogue: C = accEven + accOdd; relu(C + b2) partial column-sum
            #pragma unroll
            for (int mi = 0; mi < 2; ++mi) {
                f32x16 cfull = acc[mi][0] + acc[mi][1];
                float s = 0.f;
                #pragma unroll
                for (int r = 0; r < 16; ++r)
                    s += fmaxf(cfull[r] + bias, 0.f);
                csum += s;
            }
            flag_release_add(&cons_cnt[q], lane);
        }

        // flush: add other lane-half's rows; lanes 0-31 store 32-col partial
        csum += __shfl_xor(csum, 32);
        if (lane < 32) part[(blk * 8 + wc) * 32 + (lane & 31)] = csum;
    }
}

// K5: pooled[b][c] = sum over 4 i-quarter blocks; then f-head.
__global__ void k5_head(const float* __restrict__ part, const float* __restrict__ fw1,
                        const float* __restrict__ fb1, const float* __restrict__ fw2,
                        const float* __restrict__ fb2, float* __restrict__ out) {
    __shared__ float P[256];
    __shared__ float wsum[4];
    int b = blockIdx.x, t = threadIdx.x;
    int wc = t >> 5, cl = t & 31;
    float s0 = 0.f;
    #pragma unroll
    for (int g = 0; g < 4; ++g)
        s0 += part[((b + 64 * g) * 8 + wc) * 32 + cl];
    P[t] = s0;
    __syncthreads();
    float a0 = 0.f, a1 = 0.f, a2 = 0.f, a3 = 0.f;
    for (int k = 0; k < 64; ++k) {
        a0 += P[k]       * fw1[k * 256 + t];
        a1 += P[k + 64]  * fw1[(k + 64) * 256 + t];
        a2 += P[k + 128] * fw1[(k + 128) * 256 + t];
        a3 += P[k + 192] * fw1[(k + 192) * 256 + t];
    }
    float h = fmaxf(fb1[t] + a0 + a1 + a2 + a3, 0.f);
    float p = h * fw2[t];
    #pragma unroll
    for (int off = 32; off >= 1; off >>= 1) p += __shfl_xor(p, off);
    if ((t & 63) == 0) wsum[t >> 6] = p;
    __syncthreads();
    if (t == 0) out[b] = wsum[0] + wsum[1] + wsum[2] + wsum[3] + fb2[0];
}

extern "C" void kernel_launch(void* const* d_in, const int* in_sizes, int n_in,
                              void* d_out, int out_size, void* d_ws, size_t ws_size,
                              hipStream_t stream) {
    const float* image  = (const float*)d_in[0];
    const float* conv_w = (const float*)d_in[1];
    const float* conv_b = (const float*)d_in[2];
    const float* g_w1   = (const float*)d_in[3];
    const float* g_b1   = (const float*)d_in[4];
    const float* g_w2   = (const float*)d_in[5];
    const float* g_b2   = (const float*)d_in[6];
    const float* f_w1   = (const float*)d_in[7];
    const float* f_b1   = (const float*)d_in[8];
    const float* f_w2   = (const float*)d_in[9];
    const float* f_b2   = (const float*)d_in[10];
    float* out = (float*)d_out;

    char* ws = (char*)d_ws;
    float* u    = (float*)(ws + 0);          // 64*64*256*4 = 4 MB
    float* v    = (float*)(ws + 4194304);    // 4 MB
    short* w2f  = (short*)(ws + 8388608);    // 128 KB
    float* part = (float*)(ws + 8519680);    // 256*8*32*4 = 256 KB

    k12_front<<<288, 256, 0, stream>>>(image, conv_w, conv_b, g_w1, g_b1, g_w2,
                                       u, v, w2f);
    k3_pairs<<<256, 768, 0, stream>>>(u, v, w2f, g_b2, part);
    k5_head<<<64, 256, 0, stream>>>(part, f_w1, f_b1, f_w2, f_b2, out);
}